// Round 16
// baseline (256.221 us; speedup 1.0000x reference)
//
#include <hip/hip_runtime.h>
#include <math.h>

#define N_NODES 50000
#define N_EDGES 800000
#define IN_FEATS 128
#define N_HIDDEN 128
#define N_CLASSES 40
#define SEQ_LEN 20
#define VOCAB 32000
#define BUCKET_CAP 64     // P(in_deg >= 64 | Poisson(16)) ~ 1e-18; guarded anyway
#define EDGE_BLOCKS 1563  // ceil(800000 / (256*2))
#define POOL_BLOCKS 12500 // 4 nodes per 256-thread block
#define K1_BLOCKS (EDGE_BLOCKS + POOL_BLOCKS)   // 14063; edge blocks at b%9==0

// prep kernel block ranges
#define ZERO_BLOCKS 98    // 25088 int4 = 401408 B (in_cnt + out_cnt)
#define EMB_BLOCKS 4000   // 32000*128/4 ushort4 conversions
#define W1P_BLOCKS 64     // 16384 packed W1 elements
#define PREP_BLOCKS (ZERO_BLOCKS + EMB_BLOCKS + W1P_BLOCKS)

typedef __attribute__((ext_vector_type(8))) short bf16x8;   // 8 bf16 (4 VGPRs)
typedef __attribute__((ext_vector_type(4))) float f32x4;    // MFMA accumulator

// bf16 helpers (RNE)
__device__ inline unsigned short f2bf(float x) {
    union { float f; unsigned int u; } v; v.f = x;
    unsigned int r = v.u + 0x7FFF + ((v.u >> 16) & 1);
    return (unsigned short)(r >> 16);
}
__device__ inline float bf2f(unsigned short b) {
    union { float f; unsigned int u; } v; v.u = ((unsigned int)b) << 16;
    return v.f;
}

// ---------------- workspace layout (bytes) ----------------
//   in_cnt : 0         int[50000]            (zeroed by prep)
//   out_cnt: 200704    int[50000]            (zeroed by prep)
//   bucket : 401408    int[50000*64]   12.8 MB
//   h0bf   : 13201408  ushort[50000*128] 12.8 MB (bf16)
//   W1p    : 26001408  ushort[128*128]   32 KB (bf16, MFMA-frag-packed)
//   G1     : 26034176  ushort[50000*128] 12.8 MB (bf16)
//     emb_bf OVERLAYS G1 (8.19 MB): dead after build_pool; gemm1 writes G1 after.
//   G2     : 38834176  ushort[50000*40]   4.0 MB (bf16)   total ~42.8 MB

// ===== prep: zero counters ∥ emb f32->bf16 ∥ pack W1 into MFMA B-frag layout.
__global__ __launch_bounds__(256) void prep_kernel(
        int4* __restrict__ zero_region, const float4* __restrict__ emb4,
        ushort4* __restrict__ emb_bf4, const float* __restrict__ W1,
        unsigned short* __restrict__ W1p) {
    int b = blockIdx.x;
    int t = threadIdx.x;
    if (b < ZERO_BLOCKS) {
        int i = b * 256 + t;
        if (i < 25088) zero_region[i] = make_int4(0, 0, 0, 0);
    } else if (b < ZERO_BLOCKS + EMB_BLOCKS) {
        int i = (b - ZERO_BLOCKS) * 256 + t;   // exactly 1024000
        float4 x = emb4[i];
        ushort4 o = {f2bf(x.x), f2bf(x.y), f2bf(x.z), f2bf(x.w)};
        emb_bf4[i] = o;
    } else {
        int i = (b - ZERO_BLOCKS - EMB_BLOCKS) * 256 + t;  // exactly 16384
        int tile = i >> 9, rem = i & 511;
        int ln = rem >> 3, j = rem & 7;
        int nt = tile >> 2, kb = tile & 3;
        int k = kb * 32 + ((ln >> 4) << 3) + j;
        int n = nt * 16 + (ln & 15);
        W1p[i] = f2bf(W1[k * 128 + n]);
    }
}

// ===== K1: single-pass bucket-CSC build + out-degree histogram (fabric-atomic)
// interleaved (b%9==0) with embedding mean-pool (bf16 gather -> bf16 h0).
__global__ __launch_bounds__(256) void build_pool_kernel(
        const int* __restrict__ src, const int* __restrict__ dst,
        int* __restrict__ in_cnt, int* __restrict__ out_cnt, int* __restrict__ bucket,
        const int* __restrict__ feats, const unsigned short* __restrict__ emb_bf,
        unsigned short* __restrict__ h0bf) {
    int b = blockIdx.x;
    int t = threadIdx.x;
    if (b % 9 == 0) {
        // ---- edge path: 2 edges/thread, vectorized int2 loads
        int gid = (b / 9) * 256 + t;
        if (gid < N_EDGES / 2) {
            int2 s2 = ((const int2*)src)[gid];
            int2 d2 = ((const int2*)dst)[gid];
            int p0 = atomicAdd(&in_cnt[d2.x], 1);
            if (p0 < BUCKET_CAP) bucket[d2.x * BUCKET_CAP + p0] = s2.x;
            atomicAdd(&out_cnt[s2.x], 1);
            int p1 = atomicAdd(&in_cnt[d2.y], 1);
            if (p1 < BUCKET_CAP) bucket[d2.y * BUCKET_CAP + p1] = s2.y;
            atomicAdd(&out_cnt[s2.y], 1);
        }
    } else {
        // ---- pool path: 4 nodes/block, 64 lanes span 128 feats via ushort2
        int pb = b - b / 9 - 1;
        int v = pb * 4 + (t >> 6);
        int lane = t & 63;
        const int* tk = feats + v * SEQ_LEN;
        const ushort2* ev = (const ushort2*)emb_bf;
        float a0 = 0.f, a1 = 0.f;
        int cnt = 0;
        #pragma unroll
        for (int s = 0; s < SEQ_LEN; ++s) {
            int tok = tk[s];
            cnt += (tok != 0);
            ushort2 g = ev[tok * 64 + lane];   // pad row 0 is all-zero
            a0 += bf2f(g.x);
            a1 += bf2f(g.y);
        }
        float sc = 1.f / (float)max(cnt, 1);   // rout folded into gemm1 epilogue
        ushort2 o = {f2bf(a0 * sc), f2bf(a1 * sc)};
        ((ushort2*)h0bf)[v * 64 + lane] = o;
    }
}

// ===== gemm1 via MFMA bf16: G1 = (rout ⊙ h0) @ W1.  (verified R11: ~10 µs)
__global__ __launch_bounds__(256) void gemm1_mfma(
        const unsigned short* __restrict__ h0bf, const unsigned short* __restrict__ W1p,
        const int* __restrict__ out_cnt, unsigned short* __restrict__ G1) {
    const int wave = threadIdx.x >> 6, lane = threadIdx.x & 63;
    const int quad = lane >> 4, m = lane & 15;
    const int row0 = blockIdx.x * 64 + wave * 16;
    const int arow = min(row0 + m, N_NODES - 1);
    const unsigned short* ap = h0bf + arow * 128 + quad * 8;
    bf16x8 a0 = *(const bf16x8*)(ap + 0);
    bf16x8 a1 = *(const bf16x8*)(ap + 32);
    bf16x8 a2 = *(const bf16x8*)(ap + 64);
    bf16x8 a3 = *(const bf16x8*)(ap + 96);
    const int rbase = row0 + quad * 4;
    float rout[4];
    #pragma unroll
    for (int r = 0; r < 4; ++r) {
        int rr = min(rbase + r, N_NODES - 1);
        rout[r] = 1.f / sqrtf(fmaxf((float)out_cnt[rr], 1.f));
    }
    #pragma unroll
    for (int nt = 0; nt < 8; ++nt) {
        const unsigned short* wp = W1p + (nt * 4) * 512 + lane * 8;
        bf16x8 b0 = *(const bf16x8*)(wp + 0 * 512);
        bf16x8 b1 = *(const bf16x8*)(wp + 1 * 512);
        bf16x8 b2 = *(const bf16x8*)(wp + 2 * 512);
        bf16x8 b3 = *(const bf16x8*)(wp + 3 * 512);
        f32x4 acc = {0.f, 0.f, 0.f, 0.f};
        acc = __builtin_amdgcn_mfma_f32_16x16x32_bf16(a0, b0, acc, 0, 0, 0);
        acc = __builtin_amdgcn_mfma_f32_16x16x32_bf16(a1, b1, acc, 0, 0, 0);
        acc = __builtin_amdgcn_mfma_f32_16x16x32_bf16(a2, b2, acc, 0, 0, 0);
        acc = __builtin_amdgcn_mfma_f32_16x16x32_bf16(a3, b3, acc, 0, 0, 0);
        #pragma unroll
        for (int r = 0; r < 4; ++r) {
            int row = rbase + r;
            if (row < N_NODES)
                G1[row * 128 + nt * 16 + m] = f2bf(acc[r] * rout[r]);
        }
    }
}

// ===== spmm1 + gemm2 fused: bucket indices staged in LDS (kills per-lane
// redundant VMEM index loads); 4 nodes/block, ushort2 gathers; h1 (LDS) -> G2
__global__ __launch_bounds__(256) void spmm1g2_kernel(
        const int* __restrict__ in_cnt, const int* __restrict__ out_cnt,
        const int* __restrict__ bucket, const unsigned short* __restrict__ G,
        const float* __restrict__ b1, const float* __restrict__ W2,
        unsigned short* __restrict__ G2) {
    __shared__ int idxs[256];
    __shared__ float h1s[4][128];
    int t = threadIdx.x;
    int node = t >> 6, lane = t & 63;
    int v = blockIdx.x * 4 + node;
    // stage the 4 nodes' bucket rows (contiguous 1 KB) into LDS, coalesced
    idxs[t] = bucket[blockIdx.x * 256 + t];
    __syncthreads();
    int cnt = in_cnt[v];
    int n = min(cnt, BUCKET_CAP);
    const int* bk = &idxs[node * BUCKET_CAP];
    const ushort2* Gv = (const ushort2*)G;
    float a0 = 0.f, a1 = 0.f;
    int e = 0;
    for (; e + 8 <= n; e += 8) {
        int u0 = bk[e + 0], u1 = bk[e + 1], u2 = bk[e + 2], u3 = bk[e + 3];
        int u4 = bk[e + 4], u5 = bk[e + 5], u6 = bk[e + 6], u7 = bk[e + 7];
        ushort2 g0 = Gv[u0 * 64 + lane];
        ushort2 g1 = Gv[u1 * 64 + lane];
        ushort2 g2 = Gv[u2 * 64 + lane];
        ushort2 g3 = Gv[u3 * 64 + lane];
        ushort2 g4 = Gv[u4 * 64 + lane];
        ushort2 g5 = Gv[u5 * 64 + lane];
        ushort2 g6 = Gv[u6 * 64 + lane];
        ushort2 g7 = Gv[u7 * 64 + lane];
        a0 += ((bf2f(g0.x) + bf2f(g1.x)) + (bf2f(g2.x) + bf2f(g3.x))) +
              ((bf2f(g4.x) + bf2f(g5.x)) + (bf2f(g6.x) + bf2f(g7.x)));
        a1 += ((bf2f(g0.y) + bf2f(g1.y)) + (bf2f(g2.y) + bf2f(g3.y))) +
              ((bf2f(g4.y) + bf2f(g5.y)) + (bf2f(g6.y) + bf2f(g7.y)));
    }
    if (e + 4 <= n) {
        int u0 = bk[e + 0], u1 = bk[e + 1], u2 = bk[e + 2], u3 = bk[e + 3];
        ushort2 g0 = Gv[u0 * 64 + lane];
        ushort2 g1 = Gv[u1 * 64 + lane];
        ushort2 g2 = Gv[u2 * 64 + lane];
        ushort2 g3 = Gv[u3 * 64 + lane];
        a0 += (bf2f(g0.x) + bf2f(g1.x)) + (bf2f(g2.x) + bf2f(g3.x));
        a1 += (bf2f(g0.y) + bf2f(g1.y)) + (bf2f(g2.y) + bf2f(g3.y));
        e += 4;
    }
    for (; e < n; ++e) {
        ushort2 g = Gv[bk[e] * 64 + lane];
        a0 += bf2f(g.x);
        a1 += bf2f(g.y);
    }
    float rin = 1.f / sqrtf(fmaxf((float)cnt, 1.f));
    float rout = 1.f / sqrtf(fmaxf((float)out_cnt[v], 1.f));
    float2 bb = ((const float2*)b1)[lane];
    h1s[node][2 * lane + 0] = fmaxf(a0 * rin + bb.x, 0.f) * rout;
    h1s[node][2 * lane + 1] = fmaxf(a1 * rin + bb.y, 0.f) * rout;
    __syncthreads();
    if (lane < N_CLASSES) {
        const float* hn = h1s[node];
        float s0 = 0.f, s1 = 0.f, s2 = 0.f, s3 = 0.f;
        #pragma unroll 8
        for (int k = 0; k < 128; k += 4) {
            s0 += hn[k + 0] * W2[(k + 0) * N_CLASSES + lane];
            s1 += hn[k + 1] * W2[(k + 1) * N_CLASSES + lane];
            s2 += hn[k + 2] * W2[(k + 2) * N_CLASSES + lane];
            s3 += hn[k + 3] * W2[(k + 3) * N_CLASSES + lane];
        }
        G2[v * N_CLASSES + lane] = f2bf((s0 + s1) + (s2 + s3));
    }
}

// layer-2 aggregate (bf16 bucket-gather, LDS-staged indices) + epilogue
__global__ __launch_bounds__(256) void spmm2_kernel(
        const int* __restrict__ in_cnt, const int* __restrict__ bucket,
        const unsigned short* __restrict__ G2, const float* __restrict__ b2,
        float* __restrict__ out) {
    __shared__ int idxs[256];
    int t = threadIdx.x;
    int node = t >> 6, f = t & 63;
    int v = blockIdx.x * 4 + node;
    idxs[t] = bucket[blockIdx.x * 256 + t];
    __syncthreads();
    int cnt = in_cnt[v];
    int n = min(cnt, BUCKET_CAP);
    const int* bk = &idxs[node * BUCKET_CAP];
    if (f < N_CLASSES) {
        float acc = 0.f;
        int e = 0;
        for (; e + 8 <= n; e += 8) {
            int u0 = bk[e + 0], u1 = bk[e + 1], u2 = bk[e + 2], u3 = bk[e + 3];
            int u4 = bk[e + 4], u5 = bk[e + 5], u6 = bk[e + 6], u7 = bk[e + 7];
            acc += ((bf2f(G2[u0 * N_CLASSES + f]) + bf2f(G2[u1 * N_CLASSES + f])) +
                    (bf2f(G2[u2 * N_CLASSES + f]) + bf2f(G2[u3 * N_CLASSES + f]))) +
                   ((bf2f(G2[u4 * N_CLASSES + f]) + bf2f(G2[u5 * N_CLASSES + f])) +
                    (bf2f(G2[u6 * N_CLASSES + f]) + bf2f(G2[u7 * N_CLASSES + f])));
        }
        if (e + 4 <= n) {
            int u0 = bk[e + 0], u1 = bk[e + 1], u2 = bk[e + 2], u3 = bk[e + 3];
            acc += (bf2f(G2[u0 * N_CLASSES + f]) + bf2f(G2[u1 * N_CLASSES + f])) +
                   (bf2f(G2[u2 * N_CLASSES + f]) + bf2f(G2[u3 * N_CLASSES + f]));
            e += 4;
        }
        for (; e < n; ++e) acc += bf2f(G2[bk[e] * N_CLASSES + f]);
        float rin = 1.f / sqrtf(fmaxf((float)cnt, 1.f));
        out[v * N_CLASSES + f] = acc * rin + b2[f];
    }
}

extern "C" void kernel_launch(void* const* d_in, const int* in_sizes, int n_in,
                              void* d_out, int out_size, void* d_ws, size_t ws_size,
                              hipStream_t stream) {
    const int*   feats = (const int*)d_in[0];
    const int*   src   = (const int*)d_in[1];
    const int*   dst   = (const int*)d_in[2];
    const float* emb   = (const float*)d_in[3];
    const float* W1    = (const float*)d_in[4];
    const float* b1    = (const float*)d_in[5];
    const float* W2    = (const float*)d_in[6];
    const float* b2    = (const float*)d_in[7];
    float* out = (float*)d_out;

    char* w = (char*)d_ws;
    int*   in_cnt  = (int*)(w + 0);
    int*   out_cnt = (int*)(w + 200704);
    int*   bucket  = (int*)(w + 401408);
    unsigned short* h0bf   = (unsigned short*)(w + 13201408);
    unsigned short* W1p    = (unsigned short*)(w + 26001408);
    unsigned short* G1     = (unsigned short*)(w + 26034176);
    unsigned short* emb_bf = (unsigned short*)(w + 26034176);  // overlays G1 (dead before gemm1)
    unsigned short* G2     = (unsigned short*)(w + 38834176);

    // 1) prep: zero counters ∥ emb->bf16 ∥ W1 frag-pack
    prep_kernel<<<PREP_BLOCKS, 256, 0, stream>>>(
        (int4*)w, (const float4*)emb, (ushort4*)emb_bf, W1, W1p);
    // 2) K1: bucket-CSC build + out-degree (atomics) interleaved with mean-pool
    build_pool_kernel<<<K1_BLOCKS, 256, 0, stream>>>(
        src, dst, in_cnt, out_cnt, bucket, feats, emb_bf, h0bf);
    // 3) G1 = (rout ⊙ h0) @ W1 via MFMA bf16 (overwrites emb_bf region)
    gemm1_mfma<<<782, 256, 0, stream>>>(h0bf, W1p, out_cnt, G1);
    // 4) spmm1 + gemm2 fused -> G2 (bf16, 4 MB)
    spmm1g2_kernel<<<POOL_BLOCKS, 256, 0, stream>>>(in_cnt, out_cnt, bucket, G1, b1, W2, G2);
    // 5) out = agg(G2)*rin + b2
    spmm2_kernel<<<POOL_BLOCKS, 256, 0, stream>>>(in_cnt, bucket, G2, b2, out);
}